// Round 15
// baseline (400.146 us; speedup 1.0000x reference)
//
#include <hip/hip_runtime.h>
#include <hip/hip_bf16.h>
#include <math.h>

// ---- problem constants ----
constexpr int SEQ   = 4356;
constexpr int DIM   = 1536;
constexpr int HEADS = 12;
constexpr int HD    = 128;
constexpr int CH    = 64;           // HD/2 rope channels
constexpr int C0c   = 22;
constexpr int C1c   = 21;
constexpr int WWc   = 22;
constexpr int HHWW  = 484;
constexpr int XS    = 484;
constexpr int KVB   = 32;
constexpr int NT    = (SEQ + KVB - 1) / KVB;   // 137 tiles
constexpr int SEQP  = 4416;                    // padded V^T row pitch
constexpr size_t SD = (size_t)SEQ * DIM;

typedef float f32x4 __attribute__((ext_vector_type(4)));
typedef short bf16x8 __attribute__((ext_vector_type(8)));
typedef short bf16x4 __attribute__((ext_vector_type(4)));

__device__ inline unsigned short f2bf(float f) {
  union { float f; unsigned u; } x; x.f = f;
  return (unsigned short)((x.u + 0x7FFFu + ((x.u >> 16) & 1u)) >> 16);
}

#define GLD16(g, l)                                                                        \
  __builtin_amdgcn_global_load_lds((const __attribute__((address_space(1))) unsigned*)    \
                                       (const void*)(g),                                  \
                                   (__attribute__((address_space(3))) unsigned*)(void*)(l),\
                                   16, 0, 0)

// ============================================================
// prep: zero attn-map, mask counts, padded float4 mask table
// ============================================================
__global__ __launch_bounds__(256) void prep_kernel(const float* __restrict__ mask,
                                                   float* __restrict__ amap,
                                                   float* __restrict__ cnt,
                                                   float4* __restrict__ msk4) {
  int t = threadIdx.x;
  for (int i = t; i < 2 * SEQ; i += 256) amap[i] = 0.f;
  for (int i = t; i < 512; i += 256) {
    float4 v;
    v.x = (i < XS) ? mask[i] : 0.f;
    v.y = (i < XS) ? mask[XS + i] : 0.f;
    v.z = (i < XS) ? 1.f : 0.f;
    v.w = 0.f;
    msk4[i] = v;
  }
  float c0 = 0.f, c1 = 0.f;
  for (int i = t; i < XS; i += 256) { c0 += mask[i]; c1 += mask[XS + i]; }
  __shared__ float red0[256];
  __shared__ float red1[256];
  red0[t] = c0; red1[t] = c1;
  __syncthreads();
  for (int off = 128; off > 0; off >>= 1) {
    if (t < off) { red0[t] += red0[t + off]; red1[t] += red1[t + off]; }
    __syncthreads();
  }
  if (t == 0) { cnt[0] = red0[0]; cnt[1] = red1[0]; }
}

// zero V^T tail columns (keys SEQ..SEQP)
__global__ __launch_bounds__(256) void padzero(unsigned short* __restrict__ vt) {
  const int pad = SEQP - SEQ;
  const int total = DIM * pad;
  for (int i = blockIdx.x * 256 + threadIdx.x; i < total; i += gridDim.x * 256) {
    const int d = i / pad, c = i - d * pad;
    vt[(size_t)d * SEQP + SEQ + c] = 0;
  }
}

// f32 -> bf16 (RNE), vectorized
__global__ __launch_bounds__(256) void to_bf16(const float* __restrict__ in,
                                               unsigned short* __restrict__ out, int n4) {
  for (int i = blockIdx.x * 256 + threadIdx.x; i < n4; i += gridDim.x * 256) {
    const float4 v = ((const float4*)in)[i];
    ushort4 o;
    o.x = f2bf(v.x); o.y = f2bf(v.y); o.z = f2bf(v.z); o.w = f2bf(v.w);
    ((ushort4*)out)[i] = o;
  }
}

// 4 weight matrices in one launch (z selects)
__global__ __launch_bounds__(256) void to_bf16_w(const float* __restrict__ W0, const float* __restrict__ W1,
                                                 const float* __restrict__ W2, const float* __restrict__ W3,
                                                 unsigned short* __restrict__ o0, unsigned short* __restrict__ o1,
                                                 unsigned short* __restrict__ o2, unsigned short* __restrict__ o3,
                                                 int n4) {
  const int z = blockIdx.z;
  const float* in = (z == 0) ? W0 : (z == 1) ? W1 : (z == 2) ? W2 : W3;
  unsigned short* out = (z == 0) ? o0 : (z == 1) ? o1 : (z == 2) ? o2 : o3;
  for (int i = blockIdx.x * 256 + threadIdx.x; i < n4; i += gridDim.x * 256) {
    const float4 v = ((const float4*)in)[i];
    ushort4 o;
    o.x = f2bf(v.x); o.y = f2bf(v.y); o.z = f2bf(v.z); o.w = f2bf(v.w);
    ((ushort4*)out)[i] = o;
  }
}

// ============================================================
// combined QKV MFMA GEMM (NT): z=0 -> Q f32, z=1 -> K f32, z=2 -> V^T bf16
// ============================================================
__global__ __launch_bounds__(256) void gemm_qkv(const unsigned short* __restrict__ A,
                                                const unsigned short* __restrict__ B0,
                                                const unsigned short* __restrict__ B1,
                                                const unsigned short* __restrict__ B2,
                                                const float* __restrict__ bq,
                                                const float* __restrict__ bk,
                                                const float* __restrict__ bv,
                                                float* __restrict__ o0,
                                                float* __restrict__ o1,
                                                unsigned short* __restrict__ vtout,
                                                int M) {
  __shared__ unsigned short As[128 * 64];
  __shared__ unsigned short Bs[128 * 64];
  const int z = blockIdx.z;
  const unsigned short* B = (z == 0) ? B0 : (z == 1) ? B1 : B2;
  const float* bias = (z == 0) ? bq : (z == 1) ? bk : bv;
  const int t    = threadIdx.x;
  const int lane = t & 63;
  const int w    = t >> 6;
  const int wr   = w >> 1, wc = w & 1;
  const int bm = blockIdx.x * 128, bn = blockIdx.y * 128;
  const int lq = lane & 15, lg = lane >> 4;
  f32x4 acc[4][4] = {};
  for (int k0 = 0; k0 < DIM; k0 += 64) {
#pragma unroll
    for (int i = 0; i < 4; ++i) {
      const int idx = i * 256 + t;
      const int row = idx >> 3;
      const int c8  = (idx & 7) * 8;
      const int ga  = min(bm + row, M - 1);
      GLD16(A + (size_t)ga * DIM + k0 + c8, As + idx * 8);
      const int gb  = bn + row;
      GLD16(B + (size_t)gb * DIM + k0 + c8, Bs + idx * 8);
    }
    __syncthreads();
#pragma unroll
    for (int kk = 0; kk < 2; ++kk) {
      bf16x8 af[4], bf[4];
#pragma unroll
      for (int m = 0; m < 4; ++m)
        af[m] = *(const bf16x8*)(As + (wr * 64 + m * 16 + lq) * 64 + kk * 32 + lg * 8);
#pragma unroll
      for (int n = 0; n < 4; ++n)
        bf[n] = *(const bf16x8*)(Bs + (wc * 64 + n * 16 + lq) * 64 + kk * 32 + lg * 8);
#pragma unroll
      for (int m = 0; m < 4; ++m)
#pragma unroll
        for (int n = 0; n < 4; ++n)
          acc[m][n] = __builtin_amdgcn_mfma_f32_16x16x32_bf16(af[m], bf[n], acc[m][n], 0, 0, 0);
    }
    __syncthreads();
  }
#pragma unroll
  for (int n = 0; n < 4; ++n) {
    const int col = bn + wc * 64 + n * 16 + lq;
    const float bv2 = bias[col];
#pragma unroll
    for (int m = 0; m < 4; ++m) {
      const int rm = bm + wr * 64 + m * 16 + lg * 4;
      if (z < 2) {
        float* C = (z == 0) ? o0 : o1;
#pragma unroll
        for (int r = 0; r < 4; ++r) {
          const int row = rm + r;
          if (row < M) C[(size_t)row * DIM + col] = acc[m][n][r] + bv2;
        }
      } else {
        if (rm < M) {
          bf16x4 o;
#pragma unroll
          for (int r = 0; r < 4; ++r) o[r] = (short)f2bf(acc[m][n][r] + bv2);
          *(bf16x4*)(vtout + (size_t)col * SEQP + rm) = o;
        }
      }
    }
  }
}

// ============================================================
// single-output GEMM for the final projection (f32 out)
// ============================================================
__global__ __launch_bounds__(256) void gemm_mfma(const unsigned short* __restrict__ A,
                                                 const unsigned short* __restrict__ B,
                                                 const float* __restrict__ bias,
                                                 float* __restrict__ C, int M) {
  __shared__ unsigned short As[128 * 64];
  __shared__ unsigned short Bs[128 * 64];
  const int t    = threadIdx.x;
  const int lane = t & 63;
  const int w    = t >> 6;
  const int wr   = w >> 1, wc = w & 1;
  const int bm = blockIdx.x * 128, bn = blockIdx.y * 128;
  const int lq = lane & 15, lg = lane >> 4;
  f32x4 acc[4][4] = {};
  for (int k0 = 0; k0 < DIM; k0 += 64) {
#pragma unroll
    for (int i = 0; i < 4; ++i) {
      const int idx = i * 256 + t;
      const int row = idx >> 3;
      const int c8  = (idx & 7) * 8;
      const int ga  = min(bm + row, M - 1);
      GLD16(A + (size_t)ga * DIM + k0 + c8, As + idx * 8);
      const int gb  = bn + row;
      GLD16(B + (size_t)gb * DIM + k0 + c8, Bs + idx * 8);
    }
    __syncthreads();
#pragma unroll
    for (int kk = 0; kk < 2; ++kk) {
      bf16x8 af[4], bf[4];
#pragma unroll
      for (int m = 0; m < 4; ++m)
        af[m] = *(const bf16x8*)(As + (wr * 64 + m * 16 + lq) * 64 + kk * 32 + lg * 8);
#pragma unroll
      for (int n = 0; n < 4; ++n)
        bf[n] = *(const bf16x8*)(Bs + (wc * 64 + n * 16 + lq) * 64 + kk * 32 + lg * 8);
#pragma unroll
      for (int m = 0; m < 4; ++m)
#pragma unroll
        for (int n = 0; n < 4; ++n)
          acc[m][n] = __builtin_amdgcn_mfma_f32_16x16x32_bf16(af[m], bf[n], acc[m][n], 0, 0, 0);
    }
    __syncthreads();
  }
#pragma unroll
  for (int n = 0; n < 4; ++n) {
    const int col = bn + wc * 64 + n * 16 + lq;
    const float bv = bias[col];
#pragma unroll
    for (int m = 0; m < 4; ++m) {
      const int rm = bm + wr * 64 + m * 16 + lg * 4;
#pragma unroll
      for (int r = 0; r < 4; ++r) {
        const int row = rm + r;
        if (row < M) C[(size_t)row * DIM + col] = acc[m][n][r] + bv;
      }
    }
  }
}

// ============================================================
// RMSNorm + RoPE for Q and K in one launch (blockIdx.y selects)
// ============================================================
__global__ __launch_bounds__(256) void rms_rope2(const float* __restrict__ qy,
                                                 const float* __restrict__ ky,
                                                 const float* __restrict__ gq,
                                                 const float* __restrict__ gk,
                                                 const float* __restrict__ fcos,
                                                 const float* __restrict__ fsin,
                                                 unsigned short* __restrict__ qout,
                                                 unsigned short* __restrict__ kout) {
  const int z = blockIdx.y;
  const float* y = z ? ky : qy;
  const float* g = z ? gk : gq;
  unsigned short* outb = z ? kout : qout;
  const float scale = z ? 1.0f : 0.08838834764831845f;  // 1/sqrt(128) folded into q
  const int s = blockIdx.x;
  const float* row = y + (size_t)s * DIM;
  const int t = threadIdx.x;
  float ss = 0.f;
  for (int i = t; i < DIM / 4; i += 256) {
    const float4 v = ((const float4*)row)[i];
    ss += v.x * v.x + v.y * v.y + v.z * v.z + v.w * v.w;
  }
#pragma unroll
  for (int off = 1; off < 64; off <<= 1) ss += __shfl_xor(ss, off);
  __shared__ float wred[4];
  if ((t & 63) == 0) wred[t >> 6] = ss;
  __syncthreads();
  const float tot = wred[0] + wred[1] + wred[2] + wred[3];
  const float rs = rsqrtf(tot * (1.0f / DIM) + 1e-6f);
  const int fi  = s / HHWW;
  const int rem = s - fi * HHWW;
  const int hi  = rem / WWc;
  const int wi  = rem - hi * WWc;
  for (int p = t; p < DIM / 2; p += 256) {
    const int head = p >> 6;
    const int c    = p & 63;
    const int idx  = head * HD + 2 * c;
    const int trow = (c < C0c) ? fi : ((c < C0c + C1c) ? hi : wi);
    const float co = fcos[trow * CH + c];
    const float si = fsin[trow * CH + c];
    const float a  = row[idx] * rs * g[idx];
    const float b  = row[idx + 1] * rs * g[idx + 1];
    ushort2 pr;
    pr.x = f2bf((a * co - b * si) * scale);
    pr.y = f2bf((a * si + b * co) * scale);
    *(ushort2*)(outb + (size_t)s * DIM + idx) = pr;
  }
}

// ============================================================
// Flash attention v15: r13 dataflow (4 waves, 2 q-sets, fixed-zero
// frame, setprio, Msk-from-global per r14) + T4 pipeline:
// TRIPLE-buffered K+V (prefetch distance 2) staged via global_load_lds,
// counted s_waitcnt vmcnt(4) + raw s_barrier per tile — prefetch loads
// stay in flight across the barrier (never drain to 0 mid-loop).
// Per-thread loads/tile = 4 (2 K + 2 V) -> vmcnt(4) retires the older
// tile's 4 while the newest 4 fly. Prefetch issue AFTER the barrier
// (WAR-safe vs buf[(t+2)%3] == buf[(t-1)%3] readers).
// ============================================================
#define SOFT_QS(QS, SACC, MAP_, LAST_, KBV)                                                \
  {                                                                                        \
    float sv[8];                                                                           \
    _Pragma("unroll")                                                                      \
    for (int i = 0; i < 8; ++i) {                                                          \
      float v = SACC[i >> 2][i & 3];                                                       \
      if (LAST_) { const int key = (KBV) + (i >> 2) * 16 + lg * 4 + (i & 3);               \
                   if (key >= SEQ) v = -1e30f; }                                           \
      sv[i] = __expf(v);                                                                   \
      ls[QS] += sv[i];                                                                     \
    }                                                                                      \
    if (MAP_) {                                                                            \
      _Pragma("unroll")                                                                    \
      for (int i = 0; i < 8; ++i) {                                                        \
        const int key = (KBV) + (i >> 2) * 16 + lg * 4 + (i & 3);                          \
        const float4 mv = msk4[key];                                                       \
        n0[QS] = fmaf(sv[i], mv.x, n0[QS]);                                                \
        n1[QS] = fmaf(sv[i], mv.y, n1[QS]);                                                \
        d2[QS] = fmaf(sv[i], mv.z, d2[QS]);                                                \
      }                                                                                    \
    }                                                                                      \
    _Pragma("unroll")                                                                      \
    for (int kbi = 0; kbi < 2; ++kbi) {                                                    \
      unsigned r0, r1;                                                                     \
      asm("v_cvt_pk_bf16_f32 %0, %1, %2" : "=v"(r0) : "v"(sv[kbi*4+0]), "v"(sv[kbi*4+1])); \
      asm("v_cvt_pk_bf16_f32 %0, %1, %2" : "=v"(r1) : "v"(sv[kbi*4+2]), "v"(sv[kbi*4+3])); \
      uint2 pw; pw.x = r0; pw.y = r1;                                                      \
      *(uint2*)&Pw[QS][lq][kbi * 16 + lg * 4] = pw;                                        \
    }                                                                                      \
  }

#define TILE_BODY(KB_, MAP_, LAST_, PRE_, W0_)                                             \
  {                                                                                        \
    const int kb_ = (KB_);                                                                 \
    const int tt_ = kb_ >> 5;                                                              \
    const unsigned short* Kc = Ks[tt_ % 3];                                                \
    const unsigned short* Vc = Vs[tt_ % 3];                                                \
    if (W0_) { asm volatile("s_waitcnt vmcnt(0)" ::: "memory"); }                          \
    else     { asm volatile("s_waitcnt vmcnt(4)" ::: "memory"); }                          \
    __builtin_amdgcn_s_barrier();                                                          \
    __builtin_amdgcn_sched_barrier(0);                                                     \
    if (PRE_) {                                                                            \
      const int pb_ = (tt_ + 2) % 3;                                                       \
      unsigned short* Kn = Ks[pb_];                                                        \
      unsigned short* Vn = Vs[pb_];                                                        \
      const int kbn = kb_ + 2 * KVB;                                                       \
      _Pragma("unroll")                                                                    \
      for (int j = 0; j < 2; ++j) {                                                        \
        const int ck = t + j * 256;                                                        \
        const int kr = ck >> 4, ksl = ck & 15;                                             \
        GLD16(kh + (size_t)min(kbn + kr, SEQ - 1) * DIM + ((ksl ^ (kr & 7)) * 8),          \
              Kn + ck * 8);                                                                \
        const int vd = ck >> 2, vsl = ck & 3;                                              \
        GLD16(vh + (size_t)vd * SEQP + kbn + ((vsl ^ ((vd >> 1) & 3)) * 8),                \
              Vn + ck * 8);                                                                \
      }                                                                                    \
    }                                                                                      \
    f32x4 sacc0[2] = {}, sacc1[2] = {};                                                    \
    __builtin_amdgcn_s_setprio(1);                                                         \
    _Pragma("unroll")                                                                      \
    for (int kbi = 0; kbi < 2; ++kbi) {                                                    \
      const int krow = kbi * 16 + lq;                                                      \
      _Pragma("unroll")                                                                    \
      for (int c = 0; c < 4; ++c) {                                                        \
        const bf16x8 kf = *(const bf16x8*)(Kc + (krow * 16 + ((c * 4 + lg) ^ (krow & 7))) * 8); \
        sacc0[kbi] = __builtin_amdgcn_mfma_f32_16x16x32_bf16(kf, qf0[c], sacc0[kbi], 0, 0, 0);  \
        sacc1[kbi] = __builtin_amdgcn_mfma_f32_16x16x32_bf16(kf, qf1[c], sacc1[kbi], 0, 0, 0);  \
      }                                                                                    \
    }                                                                                      \
    __builtin_amdgcn_s_setprio(0);                                                         \
    SOFT_QS(0, sacc0, MAP_, LAST_, kb_)                                                    \
    SOFT_QS(1, sacc1, MAP_, LAST_, kb_)                                                    \
    {                                                                                      \
      const bf16x8 pf0 = *(const bf16x8*)&Pw[0][lq][lg * 8];                               \
      const bf16x8 pf1 = *(const bf16x8*)&Pw[1][lq][lg * 8];                               \
      __builtin_amdgcn_s_setprio(1);                                                       \
      _Pragma("unroll")                                                                    \
      for (int db = 0; db < 8; ++db) {                                                     \
        const int vd = db * 16 + lq;                                                       \
        const bf16x8 vf = *(const bf16x8*)(Vc + (vd * 4 + (lg ^ ((vd >> 1) & 3))) * 8);    \
        acc0[db] = __builtin_amdgcn_mfma_f32_16x16x32_bf16(vf, pf0, acc0[db], 0, 0, 0);    \
        acc1[db] = __builtin_amdgcn_mfma_f32_16x16x32_bf16(vf, pf1, acc1[db], 0, 0, 0);    \
      }                                                                                    \
      __builtin_amdgcn_s_setprio(0);                                                       \
    }                                                                                      \
  }

__global__ __launch_bounds__(256, 2) void flash_mfma(const unsigned short* __restrict__ qbuf,
                                                     const unsigned short* __restrict__ kbuf,
                                                     const unsigned short* __restrict__ vt,
                                                     const float4* __restrict__ msk4,
                                                     const float* __restrict__ cnt,
                                                     unsigned short* __restrict__ ob,
                                                     float* __restrict__ amap) {
  const int h    = blockIdx.y;
  const int t    = threadIdx.x;
  const int w    = t >> 6;
  const int lane = t & 63;
  const int lq   = lane & 15, lg = lane >> 4;
  const int qbase = blockIdx.x * 128 + w * 32;

  __shared__ __align__(16) unsigned short Ks[3][KVB * 128];  // 24 KB, src-swizzled
  __shared__ __align__(16) unsigned short Vs[3][128 * KVB];  // 24 KB, src-swizzled
  __shared__ __align__(16) unsigned short Plds[4][2][16][40];// 10 KB
  unsigned short (*Pw)[16][40] = Plds[w];

  const unsigned short* kh = kbuf + h * HD;
  const unsigned short* vh = vt + (size_t)(h * HD) * SEQP;

  const int qsrc0 = min(qbase + lq, SEQ - 1);
  const int qsrc1 = min(qbase + 16 + lq, SEQ - 1);
  bf16x8 qf0[4], qf1[4];
#pragma unroll
  for (int c = 0; c < 4; ++c) {
    qf0[c] = *(const bf16x8*)(qbuf + (size_t)qsrc0 * DIM + h * HD + c * 32 + lg * 8);
    qf1[c] = *(const bf16x8*)(qbuf + (size_t)qsrc1 * DIM + h * HD + c * 32 + lg * 8);
  }

  f32x4 acc0[8] = {}, acc1[8] = {};
  float ls[2] = {0.f, 0.f};
  float d2[2] = {0.f, 0.f}, n0[2] = {0.f, 0.f}, n1[2] = {0.f, 0.f};

  // prologue: stage L(0) then L(1) (FIFO order matters for vmcnt math)
#pragma unroll
  for (int j = 0; j < 2; ++j) {
    const int ck = t + j * 256;
    const int kr = ck >> 4, ksl = ck & 15;
    GLD16(kh + (size_t)min(kr, SEQ - 1) * DIM + ((ksl ^ (kr & 7)) * 8), Ks[0] + ck * 8);
    const int vd = ck >> 2, vsl = ck & 3;
    GLD16(vh + (size_t)vd * SEQP + ((vsl ^ ((vd >> 1) & 3)) * 8), Vs[0] + ck * 8);
  }
#pragma unroll
  for (int j = 0; j < 2; ++j) {
    const int ck = t + j * 256;
    const int kr = ck >> 4, ksl = ck & 15;
    GLD16(kh + (size_t)min(KVB + kr, SEQ - 1) * DIM + ((ksl ^ (kr & 7)) * 8), Ks[1] + ck * 8);
    const int vd = ck >> 2, vsl = ck & 3;
    GLD16(vh + (size_t)vd * SEQP + KVB + ((vsl ^ ((vd >> 1) & 3)) * 8), Vs[1] + ck * 8);
  }

  // tiles 0..15: map accumulation; 16..NT-3: plain; NT-2: no prefetch; NT-1: masked
  for (int tile = 0; tile < 16; ++tile)         TILE_BODY(tile * KVB, true,  false, true,  false);
  for (int tile = 16; tile < NT - 2; ++tile)    TILE_BODY(tile * KVB, false, false, true,  false);
  TILE_BODY((NT - 2) * KVB, false, false, false, false);
  TILE_BODY((NT - 1) * KVB, false, true,  false, true);

  // epilogue: reduce per-lane l across the 4 lane-groups, write O
#pragma unroll
  for (int qs = 0; qs < 2; ++qs) {
    ls[qs] += __shfl_xor(ls[qs], 16);
    ls[qs] += __shfl_xor(ls[qs], 32);
  }
  {
    const int qrow = qbase + lq;
    if (qrow < SEQ) {
      const float inv = 1.f / ls[0];
#pragma unroll
      for (int db = 0; db < 8; ++db) {
        bf16x4 o;
#pragma unroll
        for (int r = 0; r < 4; ++r) o[r] = (short)f2bf(acc0[db][r] * inv);
        *(bf16x4*)(ob + (size_t)qrow * DIM + h * HD + db * 16 + lg * 4) = o;
      }
    }
  }
  {
    const int qrow = qbase + 16 + lq;
    if (qrow < SEQ) {
      const float inv = 1.f / ls[1];
#pragma unroll
      for (int db = 0; db < 8; ++db) {
        bf16x4 o;
#pragma unroll
        for (int r = 0; r < 4; ++r) o[r] = (short)f2bf(acc1[db][r] * inv);
        *(bf16x4*)(ob + (size_t)qrow * DIM + h * HD + db * 16 + lg * 4) = o;
      }
    }
  }
  // attn-map: same fixed frame everywhere -> plain sums
#pragma unroll
  for (int qs = 0; qs < 2; ++qs) {
    float dd = d2[qs], a0 = n0[qs], a1 = n1[qs];
    dd += __shfl_xor(dd, 16); dd += __shfl_xor(dd, 32);
    a0 += __shfl_xor(a0, 16); a0 += __shfl_xor(a0, 32);
    a1 += __shfl_xor(a1, 16); a1 += __shfl_xor(a1, 32);
    const int qrow = qbase + qs * 16 + lq;
    if (lane < 16 && qrow < SEQ) {
      const float invd = 1.f / (dd * (float)HEADS);
      atomicAdd(&amap[qrow],       a0 * invd / cnt[0]);
      atomicAdd(&amap[SEQ + qrow], a1 * invd / cnt[1]);
    }
  }
}

// ============================================================
extern "C" void kernel_launch(void* const* d_in, const int* in_sizes, int n_in,
                              void* d_out, int out_size, void* d_ws, size_t ws_size,
                              hipStream_t stream) {
  const float* x    = (const float*)d_in[0];
  const float* Wq   = (const float*)d_in[1];
  const float* bq   = (const float*)d_in[2];
  const float* Wk   = (const float*)d_in[3];
  const float* bk   = (const float*)d_in[4];
  const float* Wv   = (const float*)d_in[5];
  const float* bv   = (const float*)d_in[6];
  const float* Wo   = (const float*)d_in[7];
  const float* bo   = (const float*)d_in[8];
  const float* gq   = (const float*)d_in[9];
  const float* gk   = (const float*)d_in[10];
  const float* fc   = (const float*)d_in[11];
  const float* fs   = (const float*)d_in[12];
  const float* mask = (const float*)d_in[13];

  float* out  = (float*)d_out;
  float* amap = out + SD;
  float* f32a = out;                                    // Q f32 scratch in d_out

  float* f32b        = (float*)d_ws;                    // SD f32 (K); later ob
  unsigned short* xb = (unsigned short*)(f32b + SD);    // SD bf16
  unsigned short* qb = xb + SD;
  unsigned short* kb = qb + SD;
  unsigned short* vt = kb + SD;                         // DIM*SEQP bf16
  unsigned short* wqb = vt + (size_t)DIM * SEQP;        // 4x DIM*DIM bf16
  unsigned short* wkb = wqb + (size_t)DIM * DIM;
  unsigned short* wvb = wkb + (size_t)DIM * DIM;
  unsigned short* wob = wvb + (size_t)DIM * DIM;
  float4* msk4 = (float4*)(wob + (size_t)DIM * DIM);    // 512
  float* cnt  = (float*)(msk4 + 512);
  unsigned short* ob = (unsigned short*)f32b;           // alias: f32b dead by then

  prep_kernel<<<1, 256, 0, stream>>>(mask, amap, cnt, msk4);
  padzero<<<64, 256, 0, stream>>>(vt);
  to_bf16<<<2048, 256, 0, stream>>>(x, xb, (int)(SD / 4));
  constexpr int W4 = DIM * DIM / 4;
  to_bf16_w<<<dim3(512, 1, 4), 256, 0, stream>>>(Wq, Wk, Wv, Wo, wqb, wkb, wvb, wob, W4);

  const dim3 gg((SEQ + 127) / 128, DIM / 128, 3);
  gemm_qkv<<<gg, 256, 0, stream>>>(xb, wqb, wkb, wvb, bq, bk, bv, f32a, f32b, vt, SEQ);

  rms_rope2<<<dim3(SEQ, 2), 256, 0, stream>>>(f32a, f32b, gq, gk, fc, fs, qb, kb);

  const dim3 fg((SEQ + 127) / 128, HEADS);
  flash_mfma<<<fg, 256, 0, stream>>>(qb, kb, vt, msk4, cnt, ob, amap);

  const dim3 go((SEQ + 127) / 128, DIM / 128);
  gemm_mfma<<<go, 256, 0, stream>>>(ob, wob, bo, out, SEQ);
}

// Round 16
// 397.141 us; speedup vs baseline: 1.0076x; 1.0076x over previous
//
#include <hip/hip_runtime.h>
#include <hip/hip_bf16.h>
#include <math.h>

// ---- problem constants ----
constexpr int SEQ   = 4356;
constexpr int DIM   = 1536;
constexpr int HEADS = 12;
constexpr int HD    = 128;
constexpr int CH    = 64;           // HD/2 rope channels
constexpr int C0c   = 22;
constexpr int C1c   = 21;
constexpr int WWc   = 22;
constexpr int HHWW  = 484;
constexpr int XS    = 484;
constexpr int KVB   = 32;
constexpr int NT    = (SEQ + KVB - 1) / KVB;   // 137 tiles
constexpr int SEQP  = 4416;                    // padded V^T row pitch
constexpr size_t SD = (size_t)SEQ * DIM;

typedef float f32x4 __attribute__((ext_vector_type(4)));
typedef short bf16x8 __attribute__((ext_vector_type(8)));
typedef short bf16x4 __attribute__((ext_vector_type(4)));

__device__ inline unsigned short f2bf(float f) {
  union { float f; unsigned u; } x; x.f = f;
  return (unsigned short)((x.u + 0x7FFFu + ((x.u >> 16) & 1u)) >> 16);
}
__device__ inline float bf2f(unsigned short u) {
  union { unsigned u; float f; } x; x.u = ((unsigned)u) << 16;
  return x.f;
}

#define GLD16(g, l)                                                                        \
  __builtin_amdgcn_global_load_lds((const __attribute__((address_space(1))) unsigned*)    \
                                       (const void*)(g),                                  \
                                   (__attribute__((address_space(3))) unsigned*)(void*)(l),\
                                   16, 0, 0)

// ============================================================
// prep: mask counts + padded float4 mask table (amap zeroed in padzero)
// ============================================================
__global__ __launch_bounds__(256) void prep_kernel(const float* __restrict__ mask,
                                                   float* __restrict__ cnt,
                                                   float4* __restrict__ msk4) {
  int t = threadIdx.x;
  for (int i = t; i < 512; i += 256) {
    float4 v;
    v.x = (i < XS) ? mask[i] : 0.f;
    v.y = (i < XS) ? mask[XS + i] : 0.f;
    v.z = (i < XS) ? 1.f : 0.f;
    v.w = 0.f;
    msk4[i] = v;
  }
  float c0 = 0.f, c1 = 0.f;
  for (int i = t; i < XS; i += 256) { c0 += mask[i]; c1 += mask[XS + i]; }
  __shared__ float red0[256];
  __shared__ float red1[256];
  red0[t] = c0; red1[t] = c1;
  __syncthreads();
  for (int off = 128; off > 0; off >>= 1) {
    if (t < off) { red0[t] += red0[t + off]; red1[t] += red1[t + off]; }
    __syncthreads();
  }
  if (t == 0) { cnt[0] = red0[0]; cnt[1] = red1[0]; }
}

// zero V^T tail columns + zero attn-map region (parallel)
__global__ __launch_bounds__(256) void padzero(unsigned short* __restrict__ vt,
                                               float* __restrict__ amap) {
  const int gid = blockIdx.x * 256 + threadIdx.x;
  const int stride = gridDim.x * 256;
  for (int i = gid; i < 2 * SEQ; i += stride) amap[i] = 0.f;
  const int pad = SEQP - SEQ;
  const int total = DIM * pad;
  for (int i = gid; i < total; i += stride) {
    const int d = i / pad, c = i - d * pad;
    vt[(size_t)d * SEQP + SEQ + c] = 0;
  }
}

// f32 -> bf16 (RNE), vectorized
__global__ __launch_bounds__(256) void to_bf16(const float* __restrict__ in,
                                               unsigned short* __restrict__ out, int n4) {
  for (int i = blockIdx.x * 256 + threadIdx.x; i < n4; i += gridDim.x * 256) {
    const float4 v = ((const float4*)in)[i];
    ushort4 o;
    o.x = f2bf(v.x); o.y = f2bf(v.y); o.z = f2bf(v.z); o.w = f2bf(v.w);
    ((ushort4*)out)[i] = o;
  }
}

// 4 weight matrices in one launch (z selects)
__global__ __launch_bounds__(256) void to_bf16_w(const float* __restrict__ W0, const float* __restrict__ W1,
                                                 const float* __restrict__ W2, const float* __restrict__ W3,
                                                 unsigned short* __restrict__ o0, unsigned short* __restrict__ o1,
                                                 unsigned short* __restrict__ o2, unsigned short* __restrict__ o3,
                                                 int n4) {
  const int z = blockIdx.z;
  const float* in = (z == 0) ? W0 : (z == 1) ? W1 : (z == 2) ? W2 : W3;
  unsigned short* out = (z == 0) ? o0 : (z == 1) ? o1 : (z == 2) ? o2 : o3;
  for (int i = blockIdx.x * 256 + threadIdx.x; i < n4; i += gridDim.x * 256) {
    const float4 v = ((const float4*)in)[i];
    ushort4 o;
    o.x = f2bf(v.x); o.y = f2bf(v.y); o.z = f2bf(v.z); o.w = f2bf(v.w);
    ((ushort4*)out)[i] = o;
  }
}

// ============================================================
// combined QKV MFMA GEMM (NT): z=0 -> Q bf16, z=1 -> K bf16,
// z=2 -> V^T bf16 (pitch SEQP). Bias added before rounding.
// ============================================================
__global__ __launch_bounds__(256) void gemm_qkv(const unsigned short* __restrict__ A,
                                                const unsigned short* __restrict__ B0,
                                                const unsigned short* __restrict__ B1,
                                                const unsigned short* __restrict__ B2,
                                                const float* __restrict__ bq,
                                                const float* __restrict__ bk,
                                                const float* __restrict__ bv,
                                                unsigned short* __restrict__ o0,
                                                unsigned short* __restrict__ o1,
                                                unsigned short* __restrict__ vtout,
                                                int M) {
  __shared__ unsigned short As[128 * 64];
  __shared__ unsigned short Bs[128 * 64];
  const int z = blockIdx.z;
  const unsigned short* B = (z == 0) ? B0 : (z == 1) ? B1 : B2;
  const float* bias = (z == 0) ? bq : (z == 1) ? bk : bv;
  const int t    = threadIdx.x;
  const int lane = t & 63;
  const int w    = t >> 6;
  const int wr   = w >> 1, wc = w & 1;
  const int bm = blockIdx.x * 128, bn = blockIdx.y * 128;
  const int lq = lane & 15, lg = lane >> 4;
  f32x4 acc[4][4] = {};
  for (int k0 = 0; k0 < DIM; k0 += 64) {
#pragma unroll
    for (int i = 0; i < 4; ++i) {
      const int idx = i * 256 + t;
      const int row = idx >> 3;
      const int c8  = (idx & 7) * 8;
      const int ga  = min(bm + row, M - 1);
      GLD16(A + (size_t)ga * DIM + k0 + c8, As + idx * 8);
      const int gb  = bn + row;
      GLD16(B + (size_t)gb * DIM + k0 + c8, Bs + idx * 8);
    }
    __syncthreads();
#pragma unroll
    for (int kk = 0; kk < 2; ++kk) {
      bf16x8 af[4], bf[4];
#pragma unroll
      for (int m = 0; m < 4; ++m)
        af[m] = *(const bf16x8*)(As + (wr * 64 + m * 16 + lq) * 64 + kk * 32 + lg * 8);
#pragma unroll
      for (int n = 0; n < 4; ++n)
        bf[n] = *(const bf16x8*)(Bs + (wc * 64 + n * 16 + lq) * 64 + kk * 32 + lg * 8);
#pragma unroll
      for (int m = 0; m < 4; ++m)
#pragma unroll
        for (int n = 0; n < 4; ++n)
          acc[m][n] = __builtin_amdgcn_mfma_f32_16x16x32_bf16(af[m], bf[n], acc[m][n], 0, 0, 0);
    }
    __syncthreads();
  }
#pragma unroll
  for (int n = 0; n < 4; ++n) {
    const int col = bn + wc * 64 + n * 16 + lq;
    const float bv2 = bias[col];
#pragma unroll
    for (int m = 0; m < 4; ++m) {
      const int rm = bm + wr * 64 + m * 16 + lg * 4;
      if (z < 2) {
        unsigned short* C = (z == 0) ? o0 : o1;
#pragma unroll
        for (int r = 0; r < 4; ++r) {
          const int row = rm + r;
          if (row < M) C[(size_t)row * DIM + col] = f2bf(acc[m][n][r] + bv2);
        }
      } else {
        if (rm < M) {
          bf16x4 o;
#pragma unroll
          for (int r = 0; r < 4; ++r) o[r] = (short)f2bf(acc[m][n][r] + bv2);
          *(bf16x4*)(vtout + (size_t)col * SEQP + rm) = o;
        }
      }
    }
  }
}

// ============================================================
// single-output GEMM for the final projection (f32 out)
// ============================================================
__global__ __launch_bounds__(256) void gemm_mfma(const unsigned short* __restrict__ A,
                                                 const unsigned short* __restrict__ B,
                                                 const float* __restrict__ bias,
                                                 float* __restrict__ C, int M) {
  __shared__ unsigned short As[128 * 64];
  __shared__ unsigned short Bs[128 * 64];
  const int t    = threadIdx.x;
  const int lane = t & 63;
  const int w    = t >> 6;
  const int wr   = w >> 1, wc = w & 1;
  const int bm = blockIdx.x * 128, bn = blockIdx.y * 128;
  const int lq = lane & 15, lg = lane >> 4;
  f32x4 acc[4][4] = {};
  for (int k0 = 0; k0 < DIM; k0 += 64) {
#pragma unroll
    for (int i = 0; i < 4; ++i) {
      const int idx = i * 256 + t;
      const int row = idx >> 3;
      const int c8  = (idx & 7) * 8;
      const int ga  = min(bm + row, M - 1);
      GLD16(A + (size_t)ga * DIM + k0 + c8, As + idx * 8);
      const int gb  = bn + row;
      GLD16(B + (size_t)gb * DIM + k0 + c8, Bs + idx * 8);
    }
    __syncthreads();
#pragma unroll
    for (int kk = 0; kk < 2; ++kk) {
      bf16x8 af[4], bf[4];
#pragma unroll
      for (int m = 0; m < 4; ++m)
        af[m] = *(const bf16x8*)(As + (wr * 64 + m * 16 + lq) * 64 + kk * 32 + lg * 8);
#pragma unroll
      for (int n = 0; n < 4; ++n)
        bf[n] = *(const bf16x8*)(Bs + (wc * 64 + n * 16 + lq) * 64 + kk * 32 + lg * 8);
#pragma unroll
      for (int m = 0; m < 4; ++m)
#pragma unroll
        for (int n = 0; n < 4; ++n)
          acc[m][n] = __builtin_amdgcn_mfma_f32_16x16x32_bf16(af[m], bf[n], acc[m][n], 0, 0, 0);
    }
    __syncthreads();
  }
#pragma unroll
  for (int n = 0; n < 4; ++n) {
    const int col = bn + wc * 64 + n * 16 + lq;
    const float bv = bias[col];
#pragma unroll
    for (int m = 0; m < 4; ++m) {
      const int rm = bm + wr * 64 + m * 16 + lg * 4;
#pragma unroll
      for (int r = 0; r < 4; ++r) {
        const int row = rm + r;
        if (row < M) C[(size_t)row * DIM + col] = acc[m][n][r] + bv;
      }
    }
  }
}

// ============================================================
// RMSNorm + RoPE, IN PLACE on bf16 Q and K (blockIdx.y selects).
// Block-local read-then-write: pass 1 reads full row (vectorized),
// barrier, pass 2 each thread rewrites only elements it owns.
// ============================================================
__global__ __launch_bounds__(256) void rms_rope2(unsigned short* __restrict__ qb,
                                                 unsigned short* __restrict__ kb,
                                                 const float* __restrict__ gq,
                                                 const float* __restrict__ gk,
                                                 const float* __restrict__ fcos,
                                                 const float* __restrict__ fsin) {
  const int z = blockIdx.y;
  unsigned short* row = (z ? kb : qb) + (size_t)blockIdx.x * DIM;
  const float* g = z ? gk : gq;
  const float scale = z ? 1.0f : 0.08838834764831845f;  // 1/sqrt(128) folded into q
  const int s = blockIdx.x;
  const int t = threadIdx.x;
  float ss = 0.f;
  for (int i = t; i < DIM / 8; i += 256) {
    const bf16x8 v = ((const bf16x8*)row)[i];
#pragma unroll
    for (int j = 0; j < 8; ++j) {
      const float f = bf2f((unsigned short)v[j]);
      ss = fmaf(f, f, ss);
    }
  }
#pragma unroll
  for (int off = 1; off < 64; off <<= 1) ss += __shfl_xor(ss, off);
  __shared__ float wred[4];
  if ((t & 63) == 0) wred[t >> 6] = ss;
  __syncthreads();
  const float tot = wred[0] + wred[1] + wred[2] + wred[3];
  const float rs = rsqrtf(tot * (1.0f / DIM) + 1e-6f);
  const int fi  = s / HHWW;
  const int rem = s - fi * HHWW;
  const int hi  = rem / WWc;
  const int wi  = rem - hi * WWc;
  for (int p = t; p < DIM / 2; p += 256) {
    const int head = p >> 6;
    const int c    = p & 63;
    const int idx  = head * HD + 2 * c;
    const int trow = (c < C0c) ? fi : ((c < C0c + C1c) ? hi : wi);
    const float co = fcos[trow * CH + c];
    const float si = fsin[trow * CH + c];
    const ushort2 in = *(const ushort2*)(row + idx);
    const float a  = bf2f(in.x) * rs * g[idx];
    const float b  = bf2f(in.y) * rs * g[idx + 1];
    ushort2 pr;
    pr.x = f2bf((a * co - b * si) * scale);
    pr.y = f2bf((a * si + b * co) * scale);
    *(ushort2*)(row + idx) = pr;
  }
}

// ============================================================
// Flash attention v15 (round-15 verified, unchanged): 4 waves,
// 2 q-sets, fixed-zero frame, setprio, triple-buffered K+V via
// global_load_lds, counted s_waitcnt vmcnt(4) + raw s_barrier.
// ============================================================
#define SOFT_QS(QS, SACC, MAP_, LAST_, KBV)                                                \
  {                                                                                        \
    float sv[8];                                                                           \
    _Pragma("unroll")                                                                      \
    for (int i = 0; i < 8; ++i) {                                                          \
      float v = SACC[i >> 2][i & 3];                                                       \
      if (LAST_) { const int key = (KBV) + (i >> 2) * 16 + lg * 4 + (i & 3);               \
                   if (key >= SEQ) v = -1e30f; }                                           \
      sv[i] = __expf(v);                                                                   \
      ls[QS] += sv[i];                                                                     \
    }                                                                                      \
    if (MAP_) {                                                                            \
      _Pragma("unroll")                                                                    \
      for (int i = 0; i < 8; ++i) {                                                        \
        const int key = (KBV) + (i >> 2) * 16 + lg * 4 + (i & 3);                          \
        const float4 mv = msk4[key];                                                       \
        n0[QS] = fmaf(sv[i], mv.x, n0[QS]);                                                \
        n1[QS] = fmaf(sv[i], mv.y, n1[QS]);                                                \
        d2[QS] = fmaf(sv[i], mv.z, d2[QS]);                                                \
      }                                                                                    \
    }                                                                                      \
    _Pragma("unroll")                                                                      \
    for (int kbi = 0; kbi < 2; ++kbi) {                                                    \
      unsigned r0, r1;                                                                     \
      asm("v_cvt_pk_bf16_f32 %0, %1, %2" : "=v"(r0) : "v"(sv[kbi*4+0]), "v"(sv[kbi*4+1])); \
      asm("v_cvt_pk_bf16_f32 %0, %1, %2" : "=v"(r1) : "v"(sv[kbi*4+2]), "v"(sv[kbi*4+3])); \
      uint2 pw; pw.x = r0; pw.y = r1;                                                      \
      *(uint2*)&Pw[QS][lq][kbi * 16 + lg * 4] = pw;                                        \
    }                                                                                      \
  }

#define TILE_BODY(KB_, MAP_, LAST_, PRE_, W0_)                                             \
  {                                                                                        \
    const int kb_ = (KB_);                                                                 \
    const int tt_ = kb_ >> 5;                                                              \
    const unsigned short* Kc = Ks[tt_ % 3];                                                \
    const unsigned short* Vc = Vs[tt_ % 3];                                                \
    if (W0_) { asm volatile("s_waitcnt vmcnt(0)" ::: "memory"); }                          \
    else     { asm volatile("s_waitcnt vmcnt(4)" ::: "memory"); }                          \
    __builtin_amdgcn_s_barrier();                                                          \
    __builtin_amdgcn_sched_barrier(0);                                                     \
    if (PRE_) {                                                                            \
      const int pb_ = (tt_ + 2) % 3;                                                       \
      unsigned short* Kn = Ks[pb_];                                                        \
      unsigned short* Vn = Vs[pb_];                                                        \
      const int kbn = kb_ + 2 * KVB;                                                       \
      _Pragma("unroll")                                                                    \
      for (int j = 0; j < 2; ++j) {                                                        \
        const int ck = t + j * 256;                                                        \
        const int kr = ck >> 4, ksl = ck & 15;                                             \
        GLD16(kh + (size_t)min(kbn + kr, SEQ - 1) * DIM + ((ksl ^ (kr & 7)) * 8),          \
              Kn + ck * 8);                                                                \
        const int vd = ck >> 2, vsl = ck & 3;                                              \
        GLD16(vh + (size_t)vd * SEQP + kbn + ((vsl ^ ((vd >> 1) & 3)) * 8),                \
              Vn + ck * 8);                                                                \
      }                                                                                    \
    }                                                                                      \
    f32x4 sacc0[2] = {}, sacc1[2] = {};                                                    \
    __builtin_amdgcn_s_setprio(1);                                                         \
    _Pragma("unroll")                                                                      \
    for (int kbi = 0; kbi < 2; ++kbi) {                                                    \
      const int krow = kbi * 16 + lq;                                                      \
      _Pragma("unroll")                                                                    \
      for (int c = 0; c < 4; ++c) {                                                        \
        const bf16x8 kf = *(const bf16x8*)(Kc + (krow * 16 + ((c * 4 + lg) ^ (krow & 7))) * 8); \
        sacc0[kbi] = __builtin_amdgcn_mfma_f32_16x16x32_bf16(kf, qf0[c], sacc0[kbi], 0, 0, 0);  \
        sacc1[kbi] = __builtin_amdgcn_mfma_f32_16x16x32_bf16(kf, qf1[c], sacc1[kbi], 0, 0, 0);  \
      }                                                                                    \
    }                                                                                      \
    __builtin_amdgcn_s_setprio(0);                                                         \
    SOFT_QS(0, sacc0, MAP_, LAST_, kb_)                                                    \
    SOFT_QS(1, sacc1, MAP_, LAST_, kb_)                                                    \
    {                                                                                      \
      const bf16x8 pf0 = *(const bf16x8*)&Pw[0][lq][lg * 8];                               \
      const bf16x8 pf1 = *(const bf16x8*)&Pw[1][lq][lg * 8];                               \
      __builtin_amdgcn_s_setprio(1);                                                       \
      _Pragma("unroll")                                                                    \
      for (int db = 0; db < 8; ++db) {                                                     \
        const int vd = db * 16 + lq;                                                       \
        const bf16x8 vf = *(const bf16x8*)(Vc + (vd * 4 + (lg ^ ((vd >> 1) & 3))) * 8);    \
        acc0[db] = __builtin_amdgcn_mfma_f32_16x16x32_bf16(vf, pf0, acc0[db], 0, 0, 0);    \
        acc1[db] = __builtin_amdgcn_mfma_f32_16x16x32_bf16(vf, pf1, acc1[db], 0, 0, 0);    \
      }                                                                                    \
      __builtin_amdgcn_s_setprio(0);                                                       \
    }                                                                                      \
  }

__global__ __launch_bounds__(256, 2) void flash_mfma(const unsigned short* __restrict__ qbuf,
                                                     const unsigned short* __restrict__ kbuf,
                                                     const unsigned short* __restrict__ vt,
                                                     const float4* __restrict__ msk4,
                                                     const float* __restrict__ cnt,
                                                     unsigned short* __restrict__ ob,
                                                     float* __restrict__ amap) {
  const int h    = blockIdx.y;
  const int t    = threadIdx.x;
  const int w    = t >> 6;
  const int lane = t & 63;
  const int lq   = lane & 15, lg = lane >> 4;
  const int qbase = blockIdx.x * 128 + w * 32;

  __shared__ __align__(16) unsigned short Ks[3][KVB * 128];  // 24 KB, src-swizzled
  __shared__ __align__(16) unsigned short Vs[3][128 * KVB];  // 24 KB, src-swizzled
  __shared__ __align__(16) unsigned short Plds[4][2][16][40];// 10 KB
  unsigned short (*Pw)[16][40] = Plds[w];

  const unsigned short* kh = kbuf + h * HD;
  const unsigned short* vh = vt + (size_t)(h * HD) * SEQP;

  const int qsrc0 = min(qbase + lq, SEQ - 1);
  const int qsrc1 = min(qbase + 16 + lq, SEQ - 1);
  bf16x8 qf0[4], qf1[4];
#pragma unroll
  for (int c = 0; c < 4; ++c) {
    qf0[c] = *(const bf16x8*)(qbuf + (size_t)qsrc0 * DIM + h * HD + c * 32 + lg * 8);
    qf1[c] = *(const bf16x8*)(qbuf + (size_t)qsrc1 * DIM + h * HD + c * 32 + lg * 8);
  }

  f32x4 acc0[8] = {}, acc1[8] = {};
  float ls[2] = {0.f, 0.f};
  float d2[2] = {0.f, 0.f}, n0[2] = {0.f, 0.f}, n1[2] = {0.f, 0.f};

  // prologue: stage L(0) then L(1) (FIFO order matters for vmcnt math)
#pragma unroll
  for (int j = 0; j < 2; ++j) {
    const int ck = t + j * 256;
    const int kr = ck >> 4, ksl = ck & 15;
    GLD16(kh + (size_t)min(kr, SEQ - 1) * DIM + ((ksl ^ (kr & 7)) * 8), Ks[0] + ck * 8);
    const int vd = ck >> 2, vsl = ck & 3;
    GLD16(vh + (size_t)vd * SEQP + ((vsl ^ ((vd >> 1) & 3)) * 8), Vs[0] + ck * 8);
  }
#pragma unroll
  for (int j = 0; j < 2; ++j) {
    const int ck = t + j * 256;
    const int kr = ck >> 4, ksl = ck & 15;
    GLD16(kh + (size_t)min(KVB + kr, SEQ - 1) * DIM + ((ksl ^ (kr & 7)) * 8), Ks[1] + ck * 8);
    const int vd = ck >> 2, vsl = ck & 3;
    GLD16(vh + (size_t)vd * SEQP + KVB + ((vsl ^ ((vd >> 1) & 3)) * 8), Vs[1] + ck * 8);
  }

  // tiles 0..15: map accumulation; 16..NT-3: plain; NT-2: no prefetch; NT-1: masked
  for (int tile = 0; tile < 16; ++tile)         TILE_BODY(tile * KVB, true,  false, true,  false);
  for (int tile = 16; tile < NT - 2; ++tile)    TILE_BODY(tile * KVB, false, false, true,  false);
  TILE_BODY((NT - 2) * KVB, false, false, false, false);
  TILE_BODY((NT - 1) * KVB, false, true,  false, true);

  // epilogue: reduce per-lane l across the 4 lane-groups, write O
#pragma unroll
  for (int qs = 0; qs < 2; ++qs) {
    ls[qs] += __shfl_xor(ls[qs], 16);
    ls[qs] += __shfl_xor(ls[qs], 32);
  }
  {
    const int qrow = qbase + lq;
    if (qrow < SEQ) {
      const float inv = 1.f / ls[0];
#pragma unroll
      for (int db = 0; db < 8; ++db) {
        bf16x4 o;
#pragma unroll
        for (int r = 0; r < 4; ++r) o[r] = (short)f2bf(acc0[db][r] * inv);
        *(bf16x4*)(ob + (size_t)qrow * DIM + h * HD + db * 16 + lg * 4) = o;
      }
    }
  }
  {
    const int qrow = qbase + 16 + lq;
    if (qrow < SEQ) {
      const float inv = 1.f / ls[1];
#pragma unroll
      for (int db = 0; db < 8; ++db) {
        bf16x4 o;
#pragma unroll
        for (int r = 0; r < 4; ++r) o[r] = (short)f2bf(acc1[db][r] * inv);
        *(bf16x4*)(ob + (size_t)qrow * DIM + h * HD + db * 16 + lg * 4) = o;
      }
    }
  }
  // attn-map: same fixed frame everywhere -> plain sums
#pragma unroll
  for (int qs = 0; qs < 2; ++qs) {
    float dd = d2[qs], a0 = n0[qs], a1 = n1[qs];
    dd += __shfl_xor(dd, 16); dd += __shfl_xor(dd, 32);
    a0 += __shfl_xor(a0, 16); a0 += __shfl_xor(a0, 32);
    a1 += __shfl_xor(a1, 16); a1 += __shfl_xor(a1, 32);
    const int qrow = qbase + qs * 16 + lq;
    if (lane < 16 && qrow < SEQ) {
      const float invd = 1.f / (dd * (float)HEADS);
      atomicAdd(&amap[qrow],       a0 * invd / cnt[0]);
      atomicAdd(&amap[SEQ + qrow], a1 * invd / cnt[1]);
    }
  }
}

// ============================================================
extern "C" void kernel_launch(void* const* d_in, const int* in_sizes, int n_in,
                              void* d_out, int out_size, void* d_ws, size_t ws_size,
                              hipStream_t stream) {
  const float* x    = (const float*)d_in[0];
  const float* Wq   = (const float*)d_in[1];
  const float* bq   = (const float*)d_in[2];
  const float* Wk   = (const float*)d_in[3];
  const float* bk   = (const float*)d_in[4];
  const float* Wv   = (const float*)d_in[5];
  const float* bv   = (const float*)d_in[6];
  const float* Wo   = (const float*)d_in[7];
  const float* bo   = (const float*)d_in[8];
  const float* gq   = (const float*)d_in[9];
  const float* gk   = (const float*)d_in[10];
  const float* fc   = (const float*)d_in[11];
  const float* fs   = (const float*)d_in[12];
  const float* mask = (const float*)d_in[13];

  float* out  = (float*)d_out;
  float* amap = out + SD;

  float* f32b        = (float*)d_ws;                    // SD f32 region; ob lives here
  unsigned short* xb = (unsigned short*)(f32b + SD);    // SD bf16
  unsigned short* qb = xb + SD;
  unsigned short* kb = qb + SD;
  unsigned short* vt = kb + SD;                         // DIM*SEQP bf16
  unsigned short* wqb = vt + (size_t)DIM * SEQP;        // 4x DIM*DIM bf16
  unsigned short* wkb = wqb + (size_t)DIM * DIM;
  unsigned short* wvb = wkb + (size_t)DIM * DIM;
  unsigned short* wob = wvb + (size_t)DIM * DIM;
  float4* msk4 = (float4*)(wob + (size_t)DIM * DIM);    // 512
  float* cnt  = (float*)(msk4 + 512);
  unsigned short* ob = (unsigned short*)f32b;           // f32b region unused otherwise

  prep_kernel<<<1, 256, 0, stream>>>(mask, cnt, msk4);
  padzero<<<64, 256, 0, stream>>>(vt, amap);
  to_bf16<<<2048, 256, 0, stream>>>(x, xb, (int)(SD / 4));
  constexpr int W4 = DIM * DIM / 4;
  to_bf16_w<<<dim3(512, 1, 4), 256, 0, stream>>>(Wq, Wk, Wv, Wo, wqb, wkb, wvb, wob, W4);

  const dim3 gg((SEQ + 127) / 128, DIM / 128, 3);
  gemm_qkv<<<gg, 256, 0, stream>>>(xb, wqb, wkb, wvb, bq, bk, bv, qb, kb, vt, SEQ);

  rms_rope2<<<dim3(SEQ, 2), 256, 0, stream>>>(qb, kb, gq, gk, fc, fs);

  const dim3 fg((SEQ + 127) / 128, HEADS);
  flash_mfma<<<fg, 256, 0, stream>>>(qb, kb, vt, msk4, cnt, ob, amap);

  const dim3 go((SEQ + 127) / 128, DIM / 128);
  gemm_mfma<<<go, 256, 0, stream>>>(ob, wob, bo, out, SEQ);
}

// Round 17
// 387.940 us; speedup vs baseline: 1.0315x; 1.0237x over previous
//
#include <hip/hip_runtime.h>
#include <hip/hip_bf16.h>
#include <math.h>

// ---- problem constants ----
constexpr int SEQ   = 4356;
constexpr int DIM   = 1536;
constexpr int HEADS = 12;
constexpr int HD    = 128;
constexpr int CH    = 64;           // HD/2 rope channels
constexpr int C0c   = 22;
constexpr int C1c   = 21;
constexpr int WWc   = 22;
constexpr int HHWW  = 484;
constexpr int XS    = 484;
constexpr int KVB   = 32;
constexpr int NT    = (SEQ + KVB - 1) / KVB;   // 137 tiles
constexpr int SEQP  = 4416;                    // padded V^T row pitch
constexpr size_t SD = (size_t)SEQ * DIM;

typedef float f32x4 __attribute__((ext_vector_type(4)));
typedef short bf16x8 __attribute__((ext_vector_type(8)));
typedef short bf16x4 __attribute__((ext_vector_type(4)));

__device__ inline unsigned short f2bf(float f) {
  union { float f; unsigned u; } x; x.f = f;
  return (unsigned short)((x.u + 0x7FFFu + ((x.u >> 16) & 1u)) >> 16);
}
__device__ inline float bf2f(unsigned short u) {
  union { unsigned u; float f; } x; x.u = ((unsigned)u) << 16;
  return x.f;
}

#define GLD16(g, l)                                                                        \
  __builtin_amdgcn_global_load_lds((const __attribute__((address_space(1))) unsigned*)    \
                                       (const void*)(g),                                  \
                                   (__attribute__((address_space(3))) unsigned*)(void*)(l),\
                                   16, 0, 0)

// ============================================================
// prep: mask counts + padded float4 mask table
// ============================================================
__global__ __launch_bounds__(256) void prep_kernel(const float* __restrict__ mask,
                                                   float* __restrict__ cnt,
                                                   float4* __restrict__ msk4) {
  int t = threadIdx.x;
  for (int i = t; i < 512; i += 256) {
    float4 v;
    v.x = (i < XS) ? mask[i] : 0.f;
    v.y = (i < XS) ? mask[XS + i] : 0.f;
    v.z = (i < XS) ? 1.f : 0.f;
    v.w = 0.f;
    msk4[i] = v;
  }
  float c0 = 0.f, c1 = 0.f;
  for (int i = t; i < XS; i += 256) { c0 += mask[i]; c1 += mask[XS + i]; }
  __shared__ float red0[256];
  __shared__ float red1[256];
  red0[t] = c0; red1[t] = c1;
  __syncthreads();
  for (int off = 128; off > 0; off >>= 1) {
    if (t < off) { red0[t] += red0[t + off]; red1[t] += red1[t + off]; }
    __syncthreads();
  }
  if (t == 0) { cnt[0] = red0[0]; cnt[1] = red1[0]; }
}

// zero V^T tail columns + zero attn-map region (parallel)
__global__ __launch_bounds__(256) void padzero(unsigned short* __restrict__ vt,
                                               float* __restrict__ amap) {
  const int gid = blockIdx.x * 256 + threadIdx.x;
  const int stride = gridDim.x * 256;
  for (int i = gid; i < 2 * SEQ; i += stride) amap[i] = 0.f;
  const int pad = SEQP - SEQ;
  const int total = DIM * pad;
  for (int i = gid; i < total; i += stride) {
    const int d = i / pad, c = i - d * pad;
    vt[(size_t)d * SEQP + SEQ + c] = 0;
  }
}

// f32 -> bf16 (RNE), vectorized
__global__ __launch_bounds__(256) void to_bf16(const float* __restrict__ in,
                                               unsigned short* __restrict__ out, int n4) {
  for (int i = blockIdx.x * 256 + threadIdx.x; i < n4; i += gridDim.x * 256) {
    const float4 v = ((const float4*)in)[i];
    ushort4 o;
    o.x = f2bf(v.x); o.y = f2bf(v.y); o.z = f2bf(v.z); o.w = f2bf(v.w);
    ((ushort4*)out)[i] = o;
  }
}

// 4 weight matrices in one launch (z selects)
__global__ __launch_bounds__(256) void to_bf16_w(const float* __restrict__ W0, const float* __restrict__ W1,
                                                 const float* __restrict__ W2, const float* __restrict__ W3,
                                                 unsigned short* __restrict__ o0, unsigned short* __restrict__ o1,
                                                 unsigned short* __restrict__ o2, unsigned short* __restrict__ o3,
                                                 int n4) {
  const int z = blockIdx.z;
  const float* in = (z == 0) ? W0 : (z == 1) ? W1 : (z == 2) ? W2 : W3;
  unsigned short* out = (z == 0) ? o0 : (z == 1) ? o1 : (z == 2) ? o2 : o3;
  for (int i = blockIdx.x * 256 + threadIdx.x; i < n4; i += gridDim.x * 256) {
    const float4 v = ((const float4*)in)[i];
    ushort4 o;
    o.x = f2bf(v.x); o.y = f2bf(v.y); o.z = f2bf(v.z); o.w = f2bf(v.w);
    ((ushort4*)out)[i] = o;
  }
}

// ============================================================
// combined QKV MFMA GEMM (NT): z=0 -> Q bf16, z=1 -> K bf16,
// z=2 -> V^T bf16 (pitch SEQP). Bias added before rounding.
// ============================================================
__global__ __launch_bounds__(256) void gemm_qkv(const unsigned short* __restrict__ A,
                                                const unsigned short* __restrict__ B0,
                                                const unsigned short* __restrict__ B1,
                                                const unsigned short* __restrict__ B2,
                                                const float* __restrict__ bq,
                                                const float* __restrict__ bk,
                                                const float* __restrict__ bv,
                                                unsigned short* __restrict__ o0,
                                                unsigned short* __restrict__ o1,
                                                unsigned short* __restrict__ vtout,
                                                int M) {
  __shared__ unsigned short As[128 * 64];
  __shared__ unsigned short Bs[128 * 64];
  const int z = blockIdx.z;
  const unsigned short* B = (z == 0) ? B0 : (z == 1) ? B1 : B2;
  const float* bias = (z == 0) ? bq : (z == 1) ? bk : bv;
  const int t    = threadIdx.x;
  const int lane = t & 63;
  const int w    = t >> 6;
  const int wr   = w >> 1, wc = w & 1;
  const int bm = blockIdx.x * 128, bn = blockIdx.y * 128;
  const int lq = lane & 15, lg = lane >> 4;
  f32x4 acc[4][4] = {};
  for (int k0 = 0; k0 < DIM; k0 += 64) {
#pragma unroll
    for (int i = 0; i < 4; ++i) {
      const int idx = i * 256 + t;
      const int row = idx >> 3;
      const int c8  = (idx & 7) * 8;
      const int ga  = min(bm + row, M - 1);
      GLD16(A + (size_t)ga * DIM + k0 + c8, As + idx * 8);
      const int gb  = bn + row;
      GLD16(B + (size_t)gb * DIM + k0 + c8, Bs + idx * 8);
    }
    __syncthreads();
#pragma unroll
    for (int kk = 0; kk < 2; ++kk) {
      bf16x8 af[4], bf[4];
#pragma unroll
      for (int m = 0; m < 4; ++m)
        af[m] = *(const bf16x8*)(As + (wr * 64 + m * 16 + lq) * 64 + kk * 32 + lg * 8);
#pragma unroll
      for (int n = 0; n < 4; ++n)
        bf[n] = *(const bf16x8*)(Bs + (wc * 64 + n * 16 + lq) * 64 + kk * 32 + lg * 8);
#pragma unroll
      for (int m = 0; m < 4; ++m)
#pragma unroll
        for (int n = 0; n < 4; ++n)
          acc[m][n] = __builtin_amdgcn_mfma_f32_16x16x32_bf16(af[m], bf[n], acc[m][n], 0, 0, 0);
    }
    __syncthreads();
  }
#pragma unroll
  for (int n = 0; n < 4; ++n) {
    const int col = bn + wc * 64 + n * 16 + lq;
    const float bv2 = bias[col];
#pragma unroll
    for (int m = 0; m < 4; ++m) {
      const int rm = bm + wr * 64 + m * 16 + lg * 4;
      if (z < 2) {
        unsigned short* C = (z == 0) ? o0 : o1;
#pragma unroll
        for (int r = 0; r < 4; ++r) {
          const int row = rm + r;
          if (row < M) C[(size_t)row * DIM + col] = f2bf(acc[m][n][r] + bv2);
        }
      } else {
        if (rm < M) {
          bf16x4 o;
#pragma unroll
          for (int r = 0; r < 4; ++r) o[r] = (short)f2bf(acc[m][n][r] + bv2);
          *(bf16x4*)(vtout + (size_t)col * SEQP + rm) = o;
        }
      }
    }
  }
}

// ============================================================
// single-output GEMM for the final projection (f32 out)
// ============================================================
__global__ __launch_bounds__(256) void gemm_mfma(const unsigned short* __restrict__ A,
                                                 const unsigned short* __restrict__ B,
                                                 const float* __restrict__ bias,
                                                 float* __restrict__ C, int M) {
  __shared__ unsigned short As[128 * 64];
  __shared__ unsigned short Bs[128 * 64];
  const int t    = threadIdx.x;
  const int lane = t & 63;
  const int w    = t >> 6;
  const int wr   = w >> 1, wc = w & 1;
  const int bm = blockIdx.x * 128, bn = blockIdx.y * 128;
  const int lq = lane & 15, lg = lane >> 4;
  f32x4 acc[4][4] = {};
  for (int k0 = 0; k0 < DIM; k0 += 64) {
#pragma unroll
    for (int i = 0; i < 4; ++i) {
      const int idx = i * 256 + t;
      const int row = idx >> 3;
      const int c8  = (idx & 7) * 8;
      const int ga  = min(bm + row, M - 1);
      GLD16(A + (size_t)ga * DIM + k0 + c8, As + idx * 8);
      const int gb  = bn + row;
      GLD16(B + (size_t)gb * DIM + k0 + c8, Bs + idx * 8);
    }
    __syncthreads();
#pragma unroll
    for (int kk = 0; kk < 2; ++kk) {
      bf16x8 af[4], bf[4];
#pragma unroll
      for (int m = 0; m < 4; ++m)
        af[m] = *(const bf16x8*)(As + (wr * 64 + m * 16 + lq) * 64 + kk * 32 + lg * 8);
#pragma unroll
      for (int n = 0; n < 4; ++n)
        bf[n] = *(const bf16x8*)(Bs + (wc * 64 + n * 16 + lq) * 64 + kk * 32 + lg * 8);
#pragma unroll
      for (int m = 0; m < 4; ++m)
#pragma unroll
        for (int n = 0; n < 4; ++n)
          acc[m][n] = __builtin_amdgcn_mfma_f32_16x16x32_bf16(af[m], bf[n], acc[m][n], 0, 0, 0);
    }
    __syncthreads();
  }
#pragma unroll
  for (int n = 0; n < 4; ++n) {
    const int col = bn + wc * 64 + n * 16 + lq;
    const float bv = bias[col];
#pragma unroll
    for (int m = 0; m < 4; ++m) {
      const int rm = bm + wr * 64 + m * 16 + lg * 4;
#pragma unroll
      for (int r = 0; r < 4; ++r) {
        const int row = rm + r;
        if (row < M) C[(size_t)row * DIM + col] = acc[m][n][r] + bv;
      }
    }
  }
}

// ============================================================
// RMSNorm + RoPE, IN PLACE on bf16 Q and K (blockIdx.y selects)
// ============================================================
__global__ __launch_bounds__(256) void rms_rope2(unsigned short* __restrict__ qb,
                                                 unsigned short* __restrict__ kb,
                                                 const float* __restrict__ gq,
                                                 const float* __restrict__ gk,
                                                 const float* __restrict__ fcos,
                                                 const float* __restrict__ fsin) {
  const int z = blockIdx.y;
  unsigned short* row = (z ? kb : qb) + (size_t)blockIdx.x * DIM;
  const float* g = z ? gk : gq;
  const float scale = z ? 1.0f : 0.08838834764831845f;  // 1/sqrt(128) folded into q
  const int s = blockIdx.x;
  const int t = threadIdx.x;
  float ss = 0.f;
  for (int i = t; i < DIM / 8; i += 256) {
    const bf16x8 v = ((const bf16x8*)row)[i];
#pragma unroll
    for (int j = 0; j < 8; ++j) {
      const float f = bf2f((unsigned short)v[j]);
      ss = fmaf(f, f, ss);
    }
  }
#pragma unroll
  for (int off = 1; off < 64; off <<= 1) ss += __shfl_xor(ss, off);
  __shared__ float wred[4];
  if ((t & 63) == 0) wred[t >> 6] = ss;
  __syncthreads();
  const float tot = wred[0] + wred[1] + wred[2] + wred[3];
  const float rs = rsqrtf(tot * (1.0f / DIM) + 1e-6f);
  const int fi  = s / HHWW;
  const int rem = s - fi * HHWW;
  const int hi  = rem / WWc;
  const int wi  = rem - hi * WWc;
  for (int p = t; p < DIM / 2; p += 256) {
    const int head = p >> 6;
    const int c    = p & 63;
    const int idx  = head * HD + 2 * c;
    const int trow = (c < C0c) ? fi : ((c < C0c + C1c) ? hi : wi);
    const float co = fcos[trow * CH + c];
    const float si = fsin[trow * CH + c];
    const ushort2 in = *(const ushort2*)(row + idx);
    const float a  = bf2f(in.x) * rs * g[idx];
    const float b  = bf2f(in.y) * rs * g[idx + 1];
    ushort2 pr;
    pr.x = f2bf((a * co - b * si) * scale);
    pr.y = f2bf((a * si + b * co) * scale);
    *(ushort2*)(row + idx) = pr;
  }
}

// ============================================================
// Flash attention v17: r15/r16 dataflow with S-PIPELINE (T15-style):
// at tile t, compute S-MFMA(t+1) (K(t+1) already LDS-resident via the
// triple buffer) BEFORE softmax(t)+PV(t) -> the softmax VALU chain of
// tile t hides under S(t+1)'s matrix work. sacc ping-pong in named
// register sets (static indexing). vmcnt(4) placed AFTER prefetch
// issue: outstanding = L(t+1)+L(t+2) = 8 -> retires exactly L(t+1).
// ============================================================
#define SOFT_QS(QS, SACC, MAP_, LAST_, KBV)                                                \
  {                                                                                        \
    float sv[8];                                                                           \
    _Pragma("unroll")                                                                      \
    for (int i = 0; i < 8; ++i) {                                                          \
      float v = SACC[i >> 2][i & 3];                                                       \
      if (LAST_) { const int key = (KBV) + (i >> 2) * 16 + lg * 4 + (i & 3);               \
                   if (key >= SEQ) v = -1e30f; }                                           \
      sv[i] = __expf(v);                                                                   \
      ls[QS] += sv[i];                                                                     \
    }                                                                                      \
    if (MAP_) {                                                                            \
      _Pragma("unroll")                                                                    \
      for (int i = 0; i < 8; ++i) {                                                        \
        const int key = (KBV) + (i >> 2) * 16 + lg * 4 + (i & 3);                          \
        const float4 mv = msk4[key];                                                       \
        n0[QS] = fmaf(sv[i], mv.x, n0[QS]);                                                \
        n1[QS] = fmaf(sv[i], mv.y, n1[QS]);                                                \
        d2[QS] = fmaf(sv[i], mv.z, d2[QS]);                                                \
      }                                                                                    \
    }                                                                                      \
    _Pragma("unroll")                                                                      \
    for (int kbi = 0; kbi < 2; ++kbi) {                                                    \
      unsigned r0, r1;                                                                     \
      asm("v_cvt_pk_bf16_f32 %0, %1, %2" : "=v"(r0) : "v"(sv[kbi*4+0]), "v"(sv[kbi*4+1])); \
      asm("v_cvt_pk_bf16_f32 %0, %1, %2" : "=v"(r1) : "v"(sv[kbi*4+2]), "v"(sv[kbi*4+3])); \
      uint2 pw; pw.x = r0; pw.y = r1;                                                      \
      *(uint2*)&Pw[QS][lq][kbi * 16 + lg * 4] = pw;                                        \
    }                                                                                      \
  }

// compute S for tile TN_ into named sacc sets (zeroed here)
#define S_MFMA(TN_, SC0, SC1)                                                              \
  {                                                                                        \
    const unsigned short* Kc_ = Ks[(TN_) % 3];                                             \
    SC0[0] = z4; SC0[1] = z4; SC1[0] = z4; SC1[1] = z4;                                    \
    __builtin_amdgcn_s_setprio(1);                                                         \
    _Pragma("unroll")                                                                      \
    for (int kbi = 0; kbi < 2; ++kbi) {                                                    \
      const int krow = kbi * 16 + lq;                                                      \
      _Pragma("unroll")                                                                    \
      for (int c = 0; c < 4; ++c) {                                                        \
        const bf16x8 kf = *(const bf16x8*)(Kc_ + (krow * 16 + ((c * 4 + lg) ^ (krow & 7))) * 8); \
        SC0[kbi] = __builtin_amdgcn_mfma_f32_16x16x32_bf16(kf, qf0[c], SC0[kbi], 0, 0, 0); \
        SC1[kbi] = __builtin_amdgcn_mfma_f32_16x16x32_bf16(kf, qf1[c], SC1[kbi], 0, 0, 0); \
      }                                                                                    \
    }                                                                                      \
    __builtin_amdgcn_s_setprio(0);                                                         \
  }

// pipelined tile body: softmax+PV of tile T_ (S in SP0/SP1), S of T_+1 into SC0/SC1
#define TILE_PIPE(T_, MAP_, PRE_, W0_, SP0, SP1, SC0, SC1)                                 \
  {                                                                                        \
    const int t_  = (T_);                                                                  \
    const int kb_ = t_ * KVB;                                                              \
    __builtin_amdgcn_s_barrier();                                                          \
    if (PRE_) {                                                                            \
      const int pb_ = (t_ + 2) % 3;                                                        \
      unsigned short* Kn = Ks[pb_];                                                        \
      unsigned short* Vn = Vs[pb_];                                                        \
      const int kbn = kb_ + 2 * KVB;                                                       \
      _Pragma("unroll")                                                                    \
      for (int j = 0; j < 2; ++j) {                                                        \
        const int ck = t + j * 256;                                                        \
        const int kr = ck >> 4, ksl = ck & 15;                                             \
        GLD16(kh + (size_t)min(kbn + kr, SEQ - 1) * DIM + ((ksl ^ (kr & 7)) * 8),          \
              Kn + ck * 8);                                                                \
        const int vd = ck >> 2, vsl = ck & 3;                                              \
        GLD16(vh + (size_t)vd * SEQP + kbn + ((vsl ^ ((vd >> 1) & 3)) * 8),                \
              Vn + ck * 8);                                                                \
      }                                                                                    \
    }                                                                                      \
    __builtin_amdgcn_sched_barrier(0);                                                     \
    if (W0_) { asm volatile("s_waitcnt vmcnt(0)" ::: "memory"); }                          \
    else     { asm volatile("s_waitcnt vmcnt(4)" ::: "memory"); }                          \
    __builtin_amdgcn_sched_barrier(0);                                                     \
    S_MFMA(t_ + 1, SC0, SC1)                                                               \
    SOFT_QS(0, SP0, MAP_, false, kb_)                                                      \
    SOFT_QS(1, SP1, MAP_, false, kb_)                                                      \
    {                                                                                      \
      const unsigned short* Vc = Vs[t_ % 3];                                               \
      const bf16x8 pf0 = *(const bf16x8*)&Pw[0][lq][lg * 8];                               \
      const bf16x8 pf1 = *(const bf16x8*)&Pw[1][lq][lg * 8];                               \
      __builtin_amdgcn_s_setprio(1);                                                       \
      _Pragma("unroll")                                                                    \
      for (int db = 0; db < 8; ++db) {                                                     \
        const int vd = db * 16 + lq;                                                       \
        const bf16x8 vf = *(const bf16x8*)(Vc + (vd * 4 + (lg ^ ((vd >> 1) & 3))) * 8);    \
        acc0[db] = __builtin_amdgcn_mfma_f32_16x16x32_bf16(vf, pf0, acc0[db], 0, 0, 0);    \
        acc1[db] = __builtin_amdgcn_mfma_f32_16x16x32_bf16(vf, pf1, acc1[db], 0, 0, 0);    \
      }                                                                                    \
      __builtin_amdgcn_s_setprio(0);                                                       \
    }                                                                                      \
  }

__global__ __launch_bounds__(256, 2) void flash_mfma(const unsigned short* __restrict__ qbuf,
                                                     const unsigned short* __restrict__ kbuf,
                                                     const unsigned short* __restrict__ vt,
                                                     const float4* __restrict__ msk4,
                                                     const float* __restrict__ cnt,
                                                     unsigned short* __restrict__ ob,
                                                     float* __restrict__ amap) {
  const int h    = blockIdx.y;
  const int t    = threadIdx.x;
  const int w    = t >> 6;
  const int lane = t & 63;
  const int lq   = lane & 15, lg = lane >> 4;
  const int qbase = blockIdx.x * 128 + w * 32;

  __shared__ __align__(16) unsigned short Ks[3][KVB * 128];  // 24 KB, src-swizzled
  __shared__ __align__(16) unsigned short Vs[3][128 * KVB];  // 24 KB, src-swizzled
  __shared__ __align__(16) unsigned short Plds[4][2][16][40];// 10 KB
  unsigned short (*Pw)[16][40] = Plds[w];

  const unsigned short* kh = kbuf + h * HD;
  const unsigned short* vh = vt + (size_t)(h * HD) * SEQP;

  const f32x4 z4 = {0.f, 0.f, 0.f, 0.f};

  const int qsrc0 = min(qbase + lq, SEQ - 1);
  const int qsrc1 = min(qbase + 16 + lq, SEQ - 1);
  bf16x8 qf0[4], qf1[4];
#pragma unroll
  for (int c = 0; c < 4; ++c) {
    qf0[c] = *(const bf16x8*)(qbuf + (size_t)qsrc0 * DIM + h * HD + c * 32 + lg * 8);
    qf1[c] = *(const bf16x8*)(qbuf + (size_t)qsrc1 * DIM + h * HD + c * 32 + lg * 8);
  }

  f32x4 acc0[8] = {}, acc1[8] = {};
  f32x4 sA0[2], sA1[2], sB0[2], sB1[2];
  float ls[2] = {0.f, 0.f};
  float d2[2] = {0.f, 0.f}, n0[2] = {0.f, 0.f}, n1[2] = {0.f, 0.f};

  // prologue: stage L(0) then L(1) (FIFO order), wait L(0), S(0) -> A
#pragma unroll
  for (int j = 0; j < 2; ++j) {
    const int ck = t + j * 256;
    const int kr = ck >> 4, ksl = ck & 15;
    GLD16(kh + (size_t)min(kr, SEQ - 1) * DIM + ((ksl ^ (kr & 7)) * 8), Ks[0] + ck * 8);
    const int vd = ck >> 2, vsl = ck & 3;
    GLD16(vh + (size_t)vd * SEQP + ((vsl ^ ((vd >> 1) & 3)) * 8), Vs[0] + ck * 8);
  }
#pragma unroll
  for (int j = 0; j < 2; ++j) {
    const int ck = t + j * 256;
    const int kr = ck >> 4, ksl = ck & 15;
    GLD16(kh + (size_t)min(KVB + kr, SEQ - 1) * DIM + ((ksl ^ (kr & 7)) * 8), Ks[1] + ck * 8);
    const int vd = ck >> 2, vsl = ck & 3;
    GLD16(vh + (size_t)vd * SEQP + KVB + ((vsl ^ ((vd >> 1) & 3)) * 8), Vs[1] + ck * 8);
  }
  asm volatile("s_waitcnt vmcnt(4)" ::: "memory");   // L(0) resident
  __builtin_amdgcn_s_barrier();
  S_MFMA(0, sA0, sA1)

  // pipelined tiles: 0..15 map, 16..133 plain, 134 (last prefetch), 135 (drain)
  for (int tt = 0; tt < 16; tt += 2) {
    TILE_PIPE(tt,     true,  true, false, sA0, sA1, sB0, sB1)
    TILE_PIPE(tt + 1, true,  true, false, sB0, sB1, sA0, sA1)
  }
  for (int tt = 16; tt < 134; tt += 2) {
    TILE_PIPE(tt,     false, true, false, sA0, sA1, sB0, sB1)
    TILE_PIPE(tt + 1, false, true, false, sB0, sB1, sA0, sA1)
  }
  TILE_PIPE(134, false, true,  false, sA0, sA1, sB0, sB1)
  TILE_PIPE(135, false, false, true,  sB0, sB1, sA0, sA1)
  // final tile 136: S already in A; masked softmax + PV, no S-next
  {
    const int kb_ = 136 * KVB;
    __builtin_amdgcn_s_barrier();
    SOFT_QS(0, sA0, false, true, kb_)
    SOFT_QS(1, sA1, false, true, kb_)
    const unsigned short* Vc = Vs[136 % 3];
    const bf16x8 pf0 = *(const bf16x8*)&Pw[0][lq][lg * 8];
    const bf16x8 pf1 = *(const bf16x8*)&Pw[1][lq][lg * 8];
#pragma unroll
    for (int db = 0; db < 8; ++db) {
      const int vd = db * 16 + lq;
      const bf16x8 vf = *(const bf16x8*)(Vc + (vd * 4 + (lg ^ ((vd >> 1) & 3))) * 8);
      acc0[db] = __builtin_amdgcn_mfma_f32_16x16x32_bf16(vf, pf0, acc0[db], 0, 0, 0);
      acc1[db] = __builtin_amdgcn_mfma_f32_16x16x32_bf16(vf, pf1, acc1[db], 0, 0, 0);
    }
  }

  // epilogue: reduce per-lane l across the 4 lane-groups, write O
#pragma unroll
  for (int qs = 0; qs < 2; ++qs) {
    ls[qs] += __shfl_xor(ls[qs], 16);
    ls[qs] += __shfl_xor(ls[qs], 32);
  }
  {
    const int qrow = qbase + lq;
    if (qrow < SEQ) {
      const float inv = 1.f / ls[0];
#pragma unroll
      for (int db = 0; db < 8; ++db) {
        bf16x4 o;
#pragma unroll
        for (int r = 0; r < 4; ++r) o[r] = (short)f2bf(acc0[db][r] * inv);
        *(bf16x4*)(ob + (size_t)qrow * DIM + h * HD + db * 16 + lg * 4) = o;
      }
    }
  }
  {
    const int qrow = qbase + 16 + lq;
    if (qrow < SEQ) {
      const float inv = 1.f / ls[1];
#pragma unroll
      for (int db = 0; db < 8; ++db) {
        bf16x4 o;
#pragma unroll
        for (int r = 0; r < 4; ++r) o[r] = (short)f2bf(acc1[db][r] * inv);
        *(bf16x4*)(ob + (size_t)qrow * DIM + h * HD + db * 16 + lg * 4) = o;
      }
    }
  }
  // attn-map: same fixed frame everywhere -> plain sums
#pragma unroll
  for (int qs = 0; qs < 2; ++qs) {
    float dd = d2[qs], a0 = n0[qs], a1 = n1[qs];
    dd += __shfl_xor(dd, 16); dd += __shfl_xor(dd, 32);
    a0 += __shfl_xor(a0, 16); a0 += __shfl_xor(a0, 32);
    a1 += __shfl_xor(a1, 16); a1 += __shfl_xor(a1, 32);
    const int qrow = qbase + qs * 16 + lq;
    if (lane < 16 && qrow < SEQ) {
      const float invd = 1.f / (dd * (float)HEADS);
      atomicAdd(&amap[qrow],       a0 * invd / cnt[0]);
      atomicAdd(&amap[SEQ + qrow], a1 * invd / cnt[1]);
    }
  }
}

// ============================================================
extern "C" void kernel_launch(void* const* d_in, const int* in_sizes, int n_in,
                              void* d_out, int out_size, void* d_ws, size_t ws_size,
                              hipStream_t stream) {
  const float* x    = (const float*)d_in[0];
  const float* Wq   = (const float*)d_in[1];
  const float* bq   = (const float*)d_in[2];
  const float* Wk   = (const float*)d_in[3];
  const float* bk   = (const float*)d_in[4];
  const float* Wv   = (const float*)d_in[5];
  const float* bv   = (const float*)d_in[6];
  const float* Wo   = (const float*)d_in[7];
  const float* bo   = (const float*)d_in[8];
  const float* gq   = (const float*)d_in[9];
  const float* gk   = (const float*)d_in[10];
  const float* fc   = (const float*)d_in[11];
  const float* fs   = (const float*)d_in[12];
  const float* mask = (const float*)d_in[13];

  float* out  = (float*)d_out;
  float* amap = out + SD;

  float* f32b        = (float*)d_ws;                    // ob region
  unsigned short* xb = (unsigned short*)(f32b + SD);    // SD bf16
  unsigned short* qb = xb + SD;
  unsigned short* kb = qb + SD;
  unsigned short* vt = kb + SD;                         // DIM*SEQP bf16
  unsigned short* wqb = vt + (size_t)DIM * SEQP;        // 4x DIM*DIM bf16
  unsigned short* wkb = wqb + (size_t)DIM * DIM;
  unsigned short* wvb = wkb + (size_t)DIM * DIM;
  unsigned short* wob = wvb + (size_t)DIM * DIM;
  float4* msk4 = (float4*)(wob + (size_t)DIM * DIM);    // 512
  float* cnt  = (float*)(msk4 + 512);
  unsigned short* ob = (unsigned short*)f32b;

  prep_kernel<<<1, 256, 0, stream>>>(mask, cnt, msk4);
  padzero<<<64, 256, 0, stream>>>(vt, amap);
  to_bf16<<<2048, 256, 0, stream>>>(x, xb, (int)(SD / 4));
  constexpr int W4 = DIM * DIM / 4;
  to_bf16_w<<<dim3(512, 1, 4), 256, 0, stream>>>(Wq, Wk, Wv, Wo, wqb, wkb, wvb, wob, W4);

  const dim3 gg((SEQ + 127) / 128, DIM / 128, 3);
  gemm_qkv<<<gg, 256, 0, stream>>>(xb, wqb, wkb, wvb, bq, bk, bv, qb, kb, vt, SEQ);

  rms_rope2<<<dim3(SEQ, 2), 256, 0, stream>>>(qb, kb, gq, gk, fc, fs);

  const dim3 fg((SEQ + 127) / 128, HEADS);
  flash_mfma<<<fg, 256, 0, stream>>>(qb, kb, vt, msk4, cnt, ob, amap);

  const dim3 go((SEQ + 127) / 128, DIM / 128);
  gemm_mfma<<<go, 256, 0, stream>>>(ob, wob, bo, out, SEQ);
}